// Round 11
// baseline (208.359 us; speedup 1.0000x reference)
//
#include <hip/hip_runtime.h>
#include <hip/hip_bf16.h>

// LambdaConv1d: B=16, C=512, N=4096, h=4, k=16, u=4, v=128, m=7
// R10: (a) gemm_mfma reverted to R7 simple 2-barrier loop (R9 dbuf was +4us);
//      (b) final_kernel: all 4 vq merged into one block — q preloaded ONCE
//      (was 4x re-fetch, 33.5->8.4MB), P_lds[128][40][4] (48KB LDS),
//      grid (N/32, B)=2048 blocks, 64 tiles/block.
// Other kernels unchanged from R7.

#define B_  16
#define C_  512
#define N_  4096
#define OT  640

typedef __bf16 bf16x8 __attribute__((ext_vector_type(8)));
typedef float  f32x4  __attribute__((ext_vector_type(4)));

// ws layout (float offsets)
static constexpr size_t PBF_OFF = 0;                                  // bf16 B*640*N
static constexpr size_t XT_OFF  = ((size_t)B_ * OT * N_) / 2;         // bf16 B*N*C
static constexpr size_t WB_OFF  = XT_OFF + ((size_t)B_ * N_ * C_) / 2;
static constexpr size_t SB_OFF  = WB_OFF + ((size_t)OT * C_) / 2;
static constexpr size_t ST_OFF  = SB_OFF + (size_t)OT * 2;            // stats B*64*2 f32
static constexpr size_t LAM_OFF = ST_OFF + (size_t)B_ * 64 * 2;
// total ~152 MB

__device__ __forceinline__ void load_lds16(const void* g, void* l) {
  __builtin_amdgcn_global_load_lds(
      (const __attribute__((address_space(1))) void*)g,
      (__attribute__((address_space(3))) void*)l, 16, 0, 0);
}

__device__ __forceinline__ unsigned short f2bf(float f) {
  __hip_bfloat16 h = __float2bfloat16(f);
  return *(unsigned short*)&h;
}
__device__ __forceinline__ float bf2f(unsigned short u) {
  union { unsigned int i; float f; } c; c.i = ((unsigned int)u) << 16; return c.f;
}

// ---------------------------------------------------------------- K0: pack
__global__ __launch_bounds__(256) void pack_kernel(
    const float* __restrict__ Wq, const float* __restrict__ gq, const float* __restrict__ bq,
    const float* __restrict__ Wk, const float* __restrict__ Wv,
    const float* __restrict__ gv, const float* __restrict__ bv,
    __hip_bfloat16* __restrict__ Wall, float* __restrict__ sb) {
  int idx = blockIdx.x * 256 + threadIdx.x;
  if (idx < OT * C_) {
    int row = idx >> 9;  // /512
    float val;
    if (row < 64)        val = Wq[idx];
    else if (row < 128)  val = Wk[idx - 64 * C_];
    else                 val = Wv[idx - 128 * C_];
    Wall[idx] = __float2bfloat16(val);
  }
  if (idx < OT) {
    const float inv = 0.99999500003749971875f;  // 1/sqrt(1+1e-5)
    float s, bi;
    if (idx < 64)       { s = gq[idx] * inv;       bi = bq[idx]; }
    else if (idx < 128) { s = 1.0f;                bi = 0.0f; }
    else                { s = gv[idx - 128] * inv; bi = bv[idx - 128]; }
    sb[idx * 2]     = s;
    sb[idx * 2 + 1] = bi;
  }
}

// ---------------------------------------------------------------- K0b: x -> xT bf16 (B,N,C)
__global__ __launch_bounds__(256) void convert_x(
    const float* __restrict__ x, __hip_bfloat16* __restrict__ xT) {
  const int n0 = blockIdx.x * 64;
  const int c0 = blockIdx.y * 64;
  const int b  = blockIdx.z;
  __shared__ float tile[64][65];
  const int t = threadIdx.x;
  const int tr = t >> 4, tc4 = (t & 15) * 4;
  const float* xb = x + ((size_t)b * C_ + c0) * N_ + n0;
#pragma unroll
  for (int i = 0; i < 4; ++i) {
    float4 v = *(const float4*)&xb[(size_t)(i * 16 + tr) * N_ + tc4];
    *(float4*)&tile[i * 16 + tr][tc4] = v;
  }
  __syncthreads();
  __hip_bfloat16* ob = xT + ((size_t)b * N_ + n0) * C_ + c0;
#pragma unroll
  for (int i = 0; i < 4; ++i) {
    int rn = i * 16 + tr;
    uint2 pk;
    __hip_bfloat16* ph = (__hip_bfloat16*)&pk;
#pragma unroll
    for (int j = 0; j < 4; ++j) ph[j] = __float2bfloat16(tile[tc4 + j][rn]);
    *(uint2*)&ob[(size_t)rn * C_ + tc4] = pk;
  }
}

// ---------------------------------------------------------------- K1: MFMA proj GEMM (R7 structure)
__global__ __launch_bounds__(256) void gemm_mfma(
    const __hip_bfloat16* __restrict__ xT, const __hip_bfloat16* __restrict__ Wb,
    const float* __restrict__ sb, __hip_bfloat16* __restrict__ pbf) {
  const int t = threadIdx.x;
  const int l = t & 63, w = t >> 6;
  const int wr = w >> 1, wc = w & 1;
  const int m0 = blockIdx.y * 128, n0 = blockIdx.x * 128;
  const int b = blockIdx.z;
  const __hip_bfloat16* xb = xT + (size_t)b * N_ * C_;

  __shared__ __hip_bfloat16 Als[128 * 32];  // [m][k] row-major
  __shared__ __hip_bfloat16 Bls[128 * 32];  // [n][k] row-major

  const int srow = w * 16 + (l >> 2);
  const int scol = (l & 3) * 8;
  const __hip_bfloat16* gA = Wb + (size_t)(m0 + srow) * C_ + scol;
  const __hip_bfloat16* gB = xb + (size_t)(n0 + srow) * C_ + scol;
  __hip_bfloat16* lA = &Als[w * 512 + l * 8];
  __hip_bfloat16* lB = &Bls[w * 512 + l * 8];

  const int fr = l & 15;
  const int kg = (l >> 4) * 8;

  f32x4 acc[4][4] = {};

  for (int c0 = 0; c0 < C_; c0 += 32) {
    __syncthreads();
#pragma unroll
    for (int i = 0; i < 2; ++i) {
      load_lds16(gA + (size_t)i * 64 * C_ + c0, lA + i * 2048);
      load_lds16(gB + (size_t)i * 64 * C_ + c0, lB + i * 2048);
    }
    __syncthreads();
    bf16x8 af[4], bfr[4];
#pragma unroll
    for (int m = 0; m < 4; ++m)
      af[m] = *(const bf16x8*)&Als[(size_t)(wr * 64 + m * 16 + fr) * 32 + kg];
#pragma unroll
    for (int n = 0; n < 4; ++n)
      bfr[n] = *(const bf16x8*)&Bls[(size_t)(wc * 64 + n * 16 + fr) * 32 + kg];
#pragma unroll
    for (int m = 0; m < 4; ++m)
#pragma unroll
      for (int n = 0; n < 4; ++n)
        acc[m][n] = __builtin_amdgcn_mfma_f32_16x16x32_bf16(af[m], bfr[n], acc[m][n], 0, 0, 0);
  }

  __hip_bfloat16* pb = pbf + (size_t)b * OT * N_;
  const int rb = (l >> 4) * 4;
#pragma unroll
  for (int m = 0; m < 4; ++m) {
#pragma unroll
    for (int r = 0; r < 4; ++r) {
      int grow = m0 + wr * 64 + m * 16 + rb + r;
      float s = sb[grow * 2], bi = sb[grow * 2 + 1];
#pragma unroll
      for (int n = 0; n < 4; ++n) {
        int gcol = n0 + wc * 64 + n * 16 + fr;
        pb[(size_t)grow * N_ + gcol] = __float2bfloat16(acc[m][n][r] * s + bi);
      }
    }
  }
}

// ---------------------------------------------------------------- K2: key-row stats (max, 1/sum_exp)
__global__ __launch_bounds__(256) void softmax_stats(
    const __hip_bfloat16* __restrict__ pbf, float* __restrict__ stats) {
  const int r = blockIdx.x, b = blockIdx.y;
  const __hip_bfloat16* row = pbf + ((size_t)b * OT + 64 + r) * N_;
  const int t = threadIdx.x;
  float f[16];
  {
    uint4 v1 = ((const uint4*)row)[t];
    uint4 v2 = ((const uint4*)row)[t + 256];
    const unsigned short* h1 = (const unsigned short*)&v1;
    const unsigned short* h2 = (const unsigned short*)&v2;
#pragma unroll
    for (int j = 0; j < 8; ++j) { f[j] = bf2f(h1[j]); f[j + 8] = bf2f(h2[j]); }
  }
  float mx = -1e30f;
#pragma unroll
  for (int j = 0; j < 16; ++j) mx = fmaxf(mx, f[j]);
  __shared__ float red[4];
#pragma unroll
  for (int off = 32; off; off >>= 1) mx = fmaxf(mx, __shfl_xor(mx, off));
  if ((t & 63) == 0) red[t >> 6] = mx;
  __syncthreads();
  mx = fmaxf(fmaxf(red[0], red[1]), fmaxf(red[2], red[3]));
  float sum = 0.f;
#pragma unroll
  for (int j = 0; j < 16; ++j) sum += __expf(f[j] - mx);
  __syncthreads();
#pragma unroll
  for (int off = 32; off; off >>= 1) sum += __shfl_xor(sum, off);
  if ((t & 63) == 0) red[t >> 6] = sum;
  __syncthreads();
  if (t == 0) {
    float s = red[0] + red[1] + red[2] + red[3];
    stats[((size_t)b * 64 + r) * 2]     = mx;
    stats[((size_t)b * 64 + r) * 2 + 1] = 1.0f / s;
  }
}

// ---------------------------------------------------------------- K3: lambda_c (MFMA, vh merged)
__global__ __launch_bounds__(256) void lambda_c_kernel(
    const __hip_bfloat16* __restrict__ pbf, const float* __restrict__ stats,
    float* __restrict__ lam) {
  const int ns = blockIdx.x;
  const int b  = blockIdx.y;
  const int nb = ns * 128;
  const int t = threadIdx.x, l = t & 63, w = t >> 6;
  __shared__ __hip_bfloat16 klds[64 * 128];  // XOR-swizzled, 16 KB

  const __hip_bfloat16* kg = pbf + ((size_t)b * OT + 64) * N_ + nb;
  const float* stb = stats + (size_t)b * 64 * 2;
#pragma unroll
  for (int i = 0; i < 4; ++i) {
    int task = i * 256 + t;            // 1024 x 16B
    int row = task >> 4, gc = task & 15;
    uint4 val = *(const uint4*)&kg[(size_t)row * N_ + gc * 8];
    float mx = stb[row * 2], ivs = stb[row * 2 + 1];
    unsigned short* hs = (unsigned short*)&val;
#pragma unroll
    for (int j = 0; j < 8; ++j)
      hs[j] = f2bf(__expf(bf2f(hs[j]) - mx) * ivs);
    int byte = (row * 256 + gc * 16) ^ (((row >> 2) & 7) << 4);
    *(uint4*)((char*)klds + byte) = val;
  }
  __syncthreads();

  const int fr = l & 15, g = l >> 4;
  const __hip_bfloat16* vg = pbf + ((size_t)b * OT + 128) * N_ + nb;
  float* lamb = lam + (size_t)b * 16 * 128;
#pragma unroll
  for (int vt = 0; vt < 2; ++vt) {
    const int vv0 = (vt * 4 + w) * 16;
    f32x4 acc = {};
#pragma unroll
    for (int ui = 0; ui < 4; ++ui) {
#pragma unroll
      for (int s = 0; s < 4; ++s) {
        const int krow = fr * 4 + ui;
        const int byte = (krow * 256 + s * 64 + g * 16) ^ (((krow >> 2) & 7) << 4);
        bf16x8 af = *(const bf16x8*)((const char*)klds + byte);
        const int vrow = (vv0 + fr) * 4 + ui;
        bf16x8 bf = *(const bf16x8*)&vg[(size_t)vrow * N_ + s * 32 + g * 8];
        acc = __builtin_amdgcn_mfma_f32_16x16x32_bf16(af, bf, acc, 0, 0, 0);
      }
    }
#pragma unroll
    for (int r = 0; r < 4; ++r)
      atomicAdd(&lamb[(g * 4 + r) * 128 + vv0 + fr], acc[r]);
  }
}

// ---------------------------------------------------------------- K4: final (vq-merged, in-reg consume)
// grid (N/32=128, B); 256 thr (4 waves). Per block: 4 hh x 128 vl x 32 nl.
// q preloaded ONCE (32 regs); P_lds[128][40][4] bf16 (40KB); lamT[128][16] (8KB).
// Main loop: 4 vq x 16 tiles; per tile: MFMA -> 16 FMA -> butterfly (3 shfl) -> store.
__global__ __launch_bounds__(256) void final_kernel(
    const __hip_bfloat16* __restrict__ pbf, const float* __restrict__ lam,
    const float* __restrict__ emb, float* __restrict__ out) {
  const int n0  = blockIdx.x * 32;
  const int b   = blockIdx.y;
  const __hip_bfloat16* qb = pbf + (size_t)b * OT * N_;
  const __hip_bfloat16* vb = pbf + ((size_t)b * OT + 128) * N_;
  const int t = threadIdx.x, l = t & 63, w = t >> 6;

  __shared__ __hip_bfloat16 P_lds[128][40][4];   // 40,960 B
  __shared__ float lamT[128][16];                //  8,192 B

  const int fr = l & 15;         // A k-row / B nl-col / D col
  const int g  = l >> 4;         // K-group
  const int rb = g * 4;          // D row base (k)
  const int gb0 = g & 1, gb1 = g >> 1;

  // emb A-frag: lane holds emb[k=fr][kap=g*8+j], kap=(dm*4+ui), 0 for kap>=28
  union { uint4 u; bf16x8 v; } ef;
  {
    unsigned short eh[8];
#pragma unroll
    for (int j = 0; j < 8; ++j) {
      int kap = g * 8 + j;
      float val = 0.f;
      if (kap < 28) val = emb[fr * 28 + (kap & 3) * 7 + (kap >> 2)];
      eh[j] = f2bf(val);
    }
    ef.u.x = eh[0] | ((unsigned)eh[1] << 16);
    ef.u.y = eh[2] | ((unsigned)eh[3] << 16);
    ef.u.z = eh[4] | ((unsigned)eh[5] << 16);
    ef.u.w = eh[6] | ((unsigned)eh[7] << 16);
  }

  // q preload (bf16), ONCE for all 4 vq
  float qreg[4][4][2];
#pragma unroll
  for (int hh = 0; hh < 4; ++hh)
#pragma unroll
    for (int r = 0; r < 4; ++r)
#pragma unroll
      for (int nt = 0; nt < 2; ++nt)
        qreg[hh][r][nt] = bf2f(*(const unsigned short*)
            &qb[(size_t)(hh * 16 + rb + r) * N_ + n0 + nt * 16 + fr]);

  // P staging: 5120 tasks = 128 vl x 40 np; 4 bf16 gathers -> one b64 write
#pragma unroll
  for (int i = 0; i < 20; ++i) {
    int task = i * 256 + t;
    int vl = task / 40;
    int np = task - vl * 40;
    int gn = n0 + np - 3;
    unsigned short hv[4];
    if (np < 38 && gn >= 0 && gn < N_) {
#pragma unroll
      for (int ui = 0; ui < 4; ++ui)
        hv[ui] = *(const unsigned short*)&vb[(size_t)(ui * 128 + vl) * N_ + gn];
    } else {
      hv[0] = hv[1] = hv[2] = hv[3] = 0;
    }
    uint2 pk;
    pk.x = hv[0] | ((unsigned)hv[1] << 16);
    pk.y = hv[2] | ((unsigned)hv[3] << 16);
    *(uint2*)&P_lds[vl][np][0] = pk;
  }
  // lamT: 2048 entries
#pragma unroll
  for (int i = 0; i < 8; ++i) {
    int idx = i * 256 + t;            // (vl, kk)
    int vl = idx >> 4, kk = idx & 15;
    lamT[vl][kk] = lam[((size_t)b * 16 + kk) * 128 + vl];
  }
  __syncthreads();

  float* obase = out + ((size_t)b * 512 + g * 128) * N_ + n0;
#pragma unroll
  for (int vq = 0; vq < 4; ++vq) {
#pragma unroll
    for (int mi = 0; mi < 16; ++mi) {
      const int vl_t = vq * 32 + w * 8 + (mi >> 1);
      const int nt   = mi & 1;
      const int nlc  = nt * 16 + fr;
      union { uint4 u; bf16x8 v; } bf;
      {
        const uint2 lo = *(const uint2*)&P_lds[vl_t][nlc + 2 * g][0];
        const uint2 hi = *(const uint2*)&P_lds[vl_t][nlc + 2 * g + 1][0];
        bf.u.x = lo.x; bf.u.y = lo.y; bf.u.z = hi.x; bf.u.w = hi.y;
      }
      f32x4 c = *(const f32x4*)&lamT[vl_t][rb];
      f32x4 d = __builtin_amdgcn_mfma_f32_16x16x32_bf16(ef.v, bf.v, c, 0, 0, 0);
      float p0 = qreg[0][0][nt] * d[0] + qreg[0][1][nt] * d[1] + qreg[0][2][nt] * d[2] + qreg[0][3][nt] * d[3];
      float p1 = qreg[1][0][nt] * d[0] + qreg[1][1][nt] * d[1] + qreg[1][2][nt] * d[2] + qreg[1][3][nt] * d[3];
      float p2 = qreg[2][0][nt] * d[0] + qreg[2][1][nt] * d[1] + qreg[2][2][nt] * d[2] + qreg[2][3][nt] * d[3];
      float p3 = qreg[3][0][nt] * d[0] + qreg[3][1][nt] * d[1] + qreg[3][2][nt] * d[2] + qreg[3][3][nt] * d[3];
      float e0 = gb0 ? p0 : p1;
      float e1 = gb0 ? p2 : p3;
      float s0 = (gb0 ? p1 : p0) + __shfl_xor(e0, 16);
      float s1 = (gb0 ? p3 : p2) + __shfl_xor(e1, 16);
      float e2 = gb1 ? s0 : s1;
      float yv = (gb1 ? s1 : s0) + __shfl_xor(e2, 32);
      obase[(size_t)vl_t * N_ + nlc] = yv;
    }
  }
}

// ---------------------------------------------------------------- launch
extern "C" void kernel_launch(void* const* d_in, const int* in_sizes, int n_in,
                              void* d_out, int out_size, void* d_ws, size_t ws_size,
                              hipStream_t stream) {
  const float* x   = (const float*)d_in[0];
  const float* Wq  = (const float*)d_in[1];
  const float* gq  = (const float*)d_in[2];
  const float* bq  = (const float*)d_in[3];
  const float* Wk  = (const float*)d_in[4];
  const float* Wv  = (const float*)d_in[5];
  const float* gv  = (const float*)d_in[6];
  const float* bv  = (const float*)d_in[7];
  const float* emb = (const float*)d_in[8];

  float* ws = (float*)d_ws;
  __hip_bfloat16* pbf   = (__hip_bfloat16*)(ws + PBF_OFF);
  __hip_bfloat16* xTb   = (__hip_bfloat16*)(ws + XT_OFF);
  __hip_bfloat16* Wallb = (__hip_bfloat16*)(ws + WB_OFF);
  float* sb    = ws + SB_OFF;
  float* stats = ws + ST_OFF;
  float* lam   = ws + LAM_OFF;
  float* out   = (float*)d_out;

  hipMemsetAsync(lam, 0, (size_t)B_ * 16 * 128 * sizeof(float), stream);
  pack_kernel<<<dim3(1280), 256, 0, stream>>>(Wq, gq, bq, Wk, Wv, gv, bv, Wallb, sb);
  convert_x<<<dim3(N_ / 64, C_ / 64, B_), 256, 0, stream>>>(x, xTb);
  gemm_mfma<<<dim3(N_ / 128, OT / 128, B_), 256, 0, stream>>>(xTb, Wallb, sb, pbf);
  softmax_stats<<<dim3(64, B_), 256, 0, stream>>>(pbf, stats);
  lambda_c_kernel<<<dim3(32, 16), 256, 0, stream>>>(pbf, stats, lam);
  final_kernel<<<dim3(N_ / 32, B_), 256, 0, stream>>>(pbf, lam, emb, out);
}

// Round 12
// 190.996 us; speedup vs baseline: 1.0909x; 1.0909x over previous
//
#include <hip/hip_runtime.h>
#include <hip/hip_bf16.h>

// LambdaConv1d: B=16, C=512, N=4096, h=4, k=16, u=4, v=128, m=7
// R11: (a) final_kernel reverted to R7 body (82us; R10 vq-merge cost occupancy);
//      (b) final grid flattened + XCD-aware swizzle (T1): adjacent n-window
//      blocks (which share P halo cache lines + q rows) now land on the SAME
//      XCD L2 -> cut P line over-fetch. swz=(flat&7)*1024+(flat>>3), bijective.
// Other kernels unchanged from R7.

#define B_  16
#define C_  512
#define N_  4096
#define OT  640

typedef __bf16 bf16x8 __attribute__((ext_vector_type(8)));
typedef float  f32x4  __attribute__((ext_vector_type(4)));

// ws layout (float offsets)
static constexpr size_t PBF_OFF = 0;                                  // bf16 B*640*N
static constexpr size_t XT_OFF  = ((size_t)B_ * OT * N_) / 2;         // bf16 B*N*C
static constexpr size_t WB_OFF  = XT_OFF + ((size_t)B_ * N_ * C_) / 2;
static constexpr size_t SB_OFF  = WB_OFF + ((size_t)OT * C_) / 2;
static constexpr size_t ST_OFF  = SB_OFF + (size_t)OT * 2;            // stats B*64*2 f32
static constexpr size_t LAM_OFF = ST_OFF + (size_t)B_ * 64 * 2;
// total ~152 MB

__device__ __forceinline__ void load_lds16(const void* g, void* l) {
  __builtin_amdgcn_global_load_lds(
      (const __attribute__((address_space(1))) void*)g,
      (__attribute__((address_space(3))) void*)l, 16, 0, 0);
}

__device__ __forceinline__ unsigned short f2bf(float f) {
  __hip_bfloat16 h = __float2bfloat16(f);
  return *(unsigned short*)&h;
}
__device__ __forceinline__ float bf2f(unsigned short u) {
  union { unsigned int i; float f; } c; c.i = ((unsigned int)u) << 16; return c.f;
}

// ---------------------------------------------------------------- K0: pack
__global__ __launch_bounds__(256) void pack_kernel(
    const float* __restrict__ Wq, const float* __restrict__ gq, const float* __restrict__ bq,
    const float* __restrict__ Wk, const float* __restrict__ Wv,
    const float* __restrict__ gv, const float* __restrict__ bv,
    __hip_bfloat16* __restrict__ Wall, float* __restrict__ sb) {
  int idx = blockIdx.x * 256 + threadIdx.x;
  if (idx < OT * C_) {
    int row = idx >> 9;  // /512
    float val;
    if (row < 64)        val = Wq[idx];
    else if (row < 128)  val = Wk[idx - 64 * C_];
    else                 val = Wv[idx - 128 * C_];
    Wall[idx] = __float2bfloat16(val);
  }
  if (idx < OT) {
    const float inv = 0.99999500003749971875f;  // 1/sqrt(1+1e-5)
    float s, bi;
    if (idx < 64)       { s = gq[idx] * inv;       bi = bq[idx]; }
    else if (idx < 128) { s = 1.0f;                bi = 0.0f; }
    else                { s = gv[idx - 128] * inv; bi = bv[idx - 128]; }
    sb[idx * 2]     = s;
    sb[idx * 2 + 1] = bi;
  }
}

// ---------------------------------------------------------------- K0b: x -> xT bf16 (B,N,C)
__global__ __launch_bounds__(256) void convert_x(
    const float* __restrict__ x, __hip_bfloat16* __restrict__ xT) {
  const int n0 = blockIdx.x * 64;
  const int c0 = blockIdx.y * 64;
  const int b  = blockIdx.z;
  __shared__ float tile[64][65];
  const int t = threadIdx.x;
  const int tr = t >> 4, tc4 = (t & 15) * 4;
  const float* xb = x + ((size_t)b * C_ + c0) * N_ + n0;
#pragma unroll
  for (int i = 0; i < 4; ++i) {
    float4 v = *(const float4*)&xb[(size_t)(i * 16 + tr) * N_ + tc4];
    *(float4*)&tile[i * 16 + tr][tc4] = v;
  }
  __syncthreads();
  __hip_bfloat16* ob = xT + ((size_t)b * N_ + n0) * C_ + c0;
#pragma unroll
  for (int i = 0; i < 4; ++i) {
    int rn = i * 16 + tr;
    uint2 pk;
    __hip_bfloat16* ph = (__hip_bfloat16*)&pk;
#pragma unroll
    for (int j = 0; j < 4; ++j) ph[j] = __float2bfloat16(tile[tc4 + j][rn]);
    *(uint2*)&ob[(size_t)rn * C_ + tc4] = pk;
  }
}

// ---------------------------------------------------------------- K1: MFMA proj GEMM (R7 structure)
__global__ __launch_bounds__(256) void gemm_mfma(
    const __hip_bfloat16* __restrict__ xT, const __hip_bfloat16* __restrict__ Wb,
    const float* __restrict__ sb, __hip_bfloat16* __restrict__ pbf) {
  const int t = threadIdx.x;
  const int l = t & 63, w = t >> 6;
  const int wr = w >> 1, wc = w & 1;
  const int m0 = blockIdx.y * 128, n0 = blockIdx.x * 128;
  const int b = blockIdx.z;
  const __hip_bfloat16* xb = xT + (size_t)b * N_ * C_;

  __shared__ __hip_bfloat16 Als[128 * 32];  // [m][k] row-major
  __shared__ __hip_bfloat16 Bls[128 * 32];  // [n][k] row-major

  const int srow = w * 16 + (l >> 2);
  const int scol = (l & 3) * 8;
  const __hip_bfloat16* gA = Wb + (size_t)(m0 + srow) * C_ + scol;
  const __hip_bfloat16* gB = xb + (size_t)(n0 + srow) * C_ + scol;
  __hip_bfloat16* lA = &Als[w * 512 + l * 8];
  __hip_bfloat16* lB = &Bls[w * 512 + l * 8];

  const int fr = l & 15;
  const int kg = (l >> 4) * 8;

  f32x4 acc[4][4] = {};

  for (int c0 = 0; c0 < C_; c0 += 32) {
    __syncthreads();
#pragma unroll
    for (int i = 0; i < 2; ++i) {
      load_lds16(gA + (size_t)i * 64 * C_ + c0, lA + i * 2048);
      load_lds16(gB + (size_t)i * 64 * C_ + c0, lB + i * 2048);
    }
    __syncthreads();
    bf16x8 af[4], bfr[4];
#pragma unroll
    for (int m = 0; m < 4; ++m)
      af[m] = *(const bf16x8*)&Als[(size_t)(wr * 64 + m * 16 + fr) * 32 + kg];
#pragma unroll
    for (int n = 0; n < 4; ++n)
      bfr[n] = *(const bf16x8*)&Bls[(size_t)(wc * 64 + n * 16 + fr) * 32 + kg];
#pragma unroll
    for (int m = 0; m < 4; ++m)
#pragma unroll
      for (int n = 0; n < 4; ++n)
        acc[m][n] = __builtin_amdgcn_mfma_f32_16x16x32_bf16(af[m], bfr[n], acc[m][n], 0, 0, 0);
  }

  __hip_bfloat16* pb = pbf + (size_t)b * OT * N_;
  const int rb = (l >> 4) * 4;
#pragma unroll
  for (int m = 0; m < 4; ++m) {
#pragma unroll
    for (int r = 0; r < 4; ++r) {
      int grow = m0 + wr * 64 + m * 16 + rb + r;
      float s = sb[grow * 2], bi = sb[grow * 2 + 1];
#pragma unroll
      for (int n = 0; n < 4; ++n) {
        int gcol = n0 + wc * 64 + n * 16 + fr;
        pb[(size_t)grow * N_ + gcol] = __float2bfloat16(acc[m][n][r] * s + bi);
      }
    }
  }
}

// ---------------------------------------------------------------- K2: key-row stats (max, 1/sum_exp)
__global__ __launch_bounds__(256) void softmax_stats(
    const __hip_bfloat16* __restrict__ pbf, float* __restrict__ stats) {
  const int r = blockIdx.x, b = blockIdx.y;
  const __hip_bfloat16* row = pbf + ((size_t)b * OT + 64 + r) * N_;
  const int t = threadIdx.x;
  float f[16];
  {
    uint4 v1 = ((const uint4*)row)[t];
    uint4 v2 = ((const uint4*)row)[t + 256];
    const unsigned short* h1 = (const unsigned short*)&v1;
    const unsigned short* h2 = (const unsigned short*)&v2;
#pragma unroll
    for (int j = 0; j < 8; ++j) { f[j] = bf2f(h1[j]); f[j + 8] = bf2f(h2[j]); }
  }
  float mx = -1e30f;
#pragma unroll
  for (int j = 0; j < 16; ++j) mx = fmaxf(mx, f[j]);
  __shared__ float red[4];
#pragma unroll
  for (int off = 32; off; off >>= 1) mx = fmaxf(mx, __shfl_xor(mx, off));
  if ((t & 63) == 0) red[t >> 6] = mx;
  __syncthreads();
  mx = fmaxf(fmaxf(red[0], red[1]), fmaxf(red[2], red[3]));
  float sum = 0.f;
#pragma unroll
  for (int j = 0; j < 16; ++j) sum += __expf(f[j] - mx);
  __syncthreads();
#pragma unroll
  for (int off = 32; off; off >>= 1) sum += __shfl_xor(sum, off);
  if ((t & 63) == 0) red[t >> 6] = sum;
  __syncthreads();
  if (t == 0) {
    float s = red[0] + red[1] + red[2] + red[3];
    stats[((size_t)b * 64 + r) * 2]     = mx;
    stats[((size_t)b * 64 + r) * 2 + 1] = 1.0f / s;
  }
}

// ---------------------------------------------------------------- K3: lambda_c (MFMA, vh merged)
__global__ __launch_bounds__(256) void lambda_c_kernel(
    const __hip_bfloat16* __restrict__ pbf, const float* __restrict__ stats,
    float* __restrict__ lam) {
  const int ns = blockIdx.x;
  const int b  = blockIdx.y;
  const int nb = ns * 128;
  const int t = threadIdx.x, l = t & 63, w = t >> 6;
  __shared__ __hip_bfloat16 klds[64 * 128];  // XOR-swizzled, 16 KB

  const __hip_bfloat16* kg = pbf + ((size_t)b * OT + 64) * N_ + nb;
  const float* stb = stats + (size_t)b * 64 * 2;
#pragma unroll
  for (int i = 0; i < 4; ++i) {
    int task = i * 256 + t;            // 1024 x 16B
    int row = task >> 4, gc = task & 15;
    uint4 val = *(const uint4*)&kg[(size_t)row * N_ + gc * 8];
    float mx = stb[row * 2], ivs = stb[row * 2 + 1];
    unsigned short* hs = (unsigned short*)&val;
#pragma unroll
    for (int j = 0; j < 8; ++j)
      hs[j] = f2bf(__expf(bf2f(hs[j]) - mx) * ivs);
    int byte = (row * 256 + gc * 16) ^ (((row >> 2) & 7) << 4);
    *(uint4*)((char*)klds + byte) = val;
  }
  __syncthreads();

  const int fr = l & 15, g = l >> 4;
  const __hip_bfloat16* vg = pbf + ((size_t)b * OT + 128) * N_ + nb;
  float* lamb = lam + (size_t)b * 16 * 128;
#pragma unroll
  for (int vt = 0; vt < 2; ++vt) {
    const int vv0 = (vt * 4 + w) * 16;
    f32x4 acc = {};
#pragma unroll
    for (int ui = 0; ui < 4; ++ui) {
#pragma unroll
      for (int s = 0; s < 4; ++s) {
        const int krow = fr * 4 + ui;
        const int byte = (krow * 256 + s * 64 + g * 16) ^ (((krow >> 2) & 7) << 4);
        bf16x8 af = *(const bf16x8*)((const char*)klds + byte);
        const int vrow = (vv0 + fr) * 4 + ui;
        bf16x8 bf = *(const bf16x8*)&vg[(size_t)vrow * N_ + s * 32 + g * 8];
        acc = __builtin_amdgcn_mfma_f32_16x16x32_bf16(af, bf, acc, 0, 0, 0);
      }
    }
#pragma unroll
    for (int r = 0; r < 4; ++r)
      atomicAdd(&lamb[(g * 4 + r) * 128 + vv0 + fr], acc[r]);
  }
}

// ---------------------------------------------------------------- K4: final (R7 body, XCD-swizzled flat grid)
// flat grid 8192 = 128 n0 x 4 vq x 16 b; swz=(flat&7)*1024+(flat>>3) gives each
// XCD a contiguous (b,vq,n) range -> adjacent n-window blocks share L2 lines.
__global__ __launch_bounds__(256) void final_kernel(
    const __hip_bfloat16* __restrict__ pbf, const float* __restrict__ lam,
    const float* __restrict__ emb, float* __restrict__ out) {
  const int swz = (blockIdx.x & 7) * 1024 + (blockIdx.x >> 3);
  const int b   = swz >> 9;
  const int vq  = (swz >> 7) & 3;
  const int n0  = (swz & 127) * 32;
  const int vv0 = vq * 32;
  const __hip_bfloat16* qb = pbf + (size_t)b * OT * N_;
  const __hip_bfloat16* vb = pbf + ((size_t)b * OT + 128) * N_;
  const int t = threadIdx.x, l = t & 63, w = t >> 6;

  __shared__ __hip_bfloat16 P_lds[32][40][4];   // 10,240 B
  __shared__ float lamT[32][16];                //  2,048 B

  const int fr = l & 15;         // A k-row / B nl-col / D col
  const int g  = l >> 4;         // K-group
  const int rb = g * 4;          // D row base (k)
  const int gb0 = g & 1, gb1 = g >> 1;

  // emb A-frag: lane holds emb[k=fr][kap=g*8+j], kap=(dm*4+ui), 0 for kap>=28
  union { uint4 u; bf16x8 v; } ef;
  {
    unsigned short eh[8];
#pragma unroll
    for (int j = 0; j < 8; ++j) {
      int kap = g * 8 + j;
      float val = 0.f;
      if (kap < 28) val = emb[fr * 28 + (kap & 3) * 7 + (kap >> 2)];
      eh[j] = f2bf(val);
    }
    ef.u.x = eh[0] | ((unsigned)eh[1] << 16);
    ef.u.y = eh[2] | ((unsigned)eh[3] << 16);
    ef.u.z = eh[4] | ((unsigned)eh[5] << 16);
    ef.u.w = eh[6] | ((unsigned)eh[7] << 16);
  }

  // q preload (bf16)
  float qreg[4][4][2];
#pragma unroll
  for (int hh = 0; hh < 4; ++hh)
#pragma unroll
    for (int r = 0; r < 4; ++r)
#pragma unroll
      for (int nt = 0; nt < 2; ++nt)
        qreg[hh][r][nt] = bf2f(*(const unsigned short*)
            &qb[(size_t)(hh * 16 + rb + r) * N_ + n0 + nt * 16 + fr]);

  // P staging: task=(vl,np); 4 bf16 gathers -> one b64 LDS write
#pragma unroll
  for (int i = 0; i < 5; ++i) {
    int task = i * 256 + t;              // 1280 = 32 vl * 40 np
    int vl = task / 40;
    int np = task - vl * 40;
    int gn = n0 + np - 3;
    unsigned short hv[4];
    if (np < 38 && gn >= 0 && gn < N_) {
#pragma unroll
      for (int ui = 0; ui < 4; ++ui)
        hv[ui] = *(const unsigned short*)&vb[(size_t)(ui * 128 + vv0 + vl) * N_ + gn];
    } else {
      hv[0] = hv[1] = hv[2] = hv[3] = 0;
    }
    uint2 pk;
    pk.x = hv[0] | ((unsigned)hv[1] << 16);
    pk.y = hv[2] | ((unsigned)hv[3] << 16);
    *(uint2*)&P_lds[vl][np][0] = pk;
  }
  // lamT
  {
    int kk = t >> 5, vl = t & 31;
    lamT[vl][kk]     = lam[((size_t)b * 16 + kk) * 128 + vv0 + vl];
    lamT[vl][kk + 8] = lam[((size_t)b * 16 + kk + 8) * 128 + vv0 + vl];
  }
  __syncthreads();

  float* obase = out + ((size_t)b * 512 + g * 128 + vv0) * N_ + n0;
#pragma unroll
  for (int mi = 0; mi < 16; ++mi) {
    const int vl_t = w * 8 + (mi >> 1);
    const int nt   = mi & 1;
    const int nlc  = nt * 16 + fr;
    union { uint4 u; bf16x8 v; } bf;
    {
      const uint2 lo = *(const uint2*)&P_lds[vl_t][nlc + 2 * g][0];
      const uint2 hi = *(const uint2*)&P_lds[vl_t][nlc + 2 * g + 1][0];
      bf.u.x = lo.x; bf.u.y = lo.y; bf.u.z = hi.x; bf.u.w = hi.y;
    }
    f32x4 c = *(const f32x4*)&lamT[vl_t][rb];
    f32x4 d = __builtin_amdgcn_mfma_f32_16x16x32_bf16(ef.v, bf.v, c, 0, 0, 0);
    float p0 = qreg[0][0][nt] * d[0] + qreg[0][1][nt] * d[1] + qreg[0][2][nt] * d[2] + qreg[0][3][nt] * d[3];
    float p1 = qreg[1][0][nt] * d[0] + qreg[1][1][nt] * d[1] + qreg[1][2][nt] * d[2] + qreg[1][3][nt] * d[3];
    float p2 = qreg[2][0][nt] * d[0] + qreg[2][1][nt] * d[1] + qreg[2][2][nt] * d[2] + qreg[2][3][nt] * d[3];
    float p3 = qreg[3][0][nt] * d[0] + qreg[3][1][nt] * d[1] + qreg[3][2][nt] * d[2] + qreg[3][3][nt] * d[3];
    float e0 = gb0 ? p0 : p1;
    float e1 = gb0 ? p2 : p3;
    float s0 = (gb0 ? p1 : p0) + __shfl_xor(e0, 16);
    float s1 = (gb0 ? p3 : p2) + __shfl_xor(e1, 16);
    float e2 = gb1 ? s0 : s1;
    float yv = (gb1 ? s1 : s0) + __shfl_xor(e2, 32);
    obase[(size_t)vl_t * N_ + nlc] = yv;
  }
}

// ---------------------------------------------------------------- launch
extern "C" void kernel_launch(void* const* d_in, const int* in_sizes, int n_in,
                              void* d_out, int out_size, void* d_ws, size_t ws_size,
                              hipStream_t stream) {
  const float* x   = (const float*)d_in[0];
  const float* Wq  = (const float*)d_in[1];
  const float* gq  = (const float*)d_in[2];
  const float* bq  = (const float*)d_in[3];
  const float* Wk  = (const float*)d_in[4];
  const float* Wv  = (const float*)d_in[5];
  const float* gv  = (const float*)d_in[6];
  const float* bv  = (const float*)d_in[7];
  const float* emb = (const float*)d_in[8];

  float* ws = (float*)d_ws;
  __hip_bfloat16* pbf   = (__hip_bfloat16*)(ws + PBF_OFF);
  __hip_bfloat16* xTb   = (__hip_bfloat16*)(ws + XT_OFF);
  __hip_bfloat16* Wallb = (__hip_bfloat16*)(ws + WB_OFF);
  float* sb    = ws + SB_OFF;
  float* stats = ws + ST_OFF;
  float* lam   = ws + LAM_OFF;
  float* out   = (float*)d_out;

  hipMemsetAsync(lam, 0, (size_t)B_ * 16 * 128 * sizeof(float), stream);
  pack_kernel<<<dim3(1280), 256, 0, stream>>>(Wq, gq, bq, Wk, Wv, gv, bv, Wallb, sb);
  convert_x<<<dim3(N_ / 64, C_ / 64, B_), 256, 0, stream>>>(x, xTb);
  gemm_mfma<<<dim3(N_ / 128, OT / 128, B_), 256, 0, stream>>>(xTb, Wallb, sb, pbf);
  softmax_stats<<<dim3(64, B_), 256, 0, stream>>>(pbf, stats);
  lambda_c_kernel<<<dim3(32, 16), 256, 0, stream>>>(pbf, stats, lam);
  final_kernel<<<dim3(8192), 256, 0, stream>>>(pbf, lam, emb, out);
}

// Round 13
// 185.786 us; speedup vs baseline: 1.1215x; 1.0280x over previous
//
#include <hip/hip_runtime.h>
#include <hip/hip_bf16.h>

// LambdaConv1d: B=16, C=512, N=4096, h=4, k=16, u=4, v=128, m=7
// R13: final_kernel staging rewritten — P rows loaded via global_load_lds
//   (16B/lane) into plane LDS Pstg[ui][vl][64] (window n0-8..n0+55, edge-clamped),
//   then LDS->LDS repack into packed P_lds[vl][np][ui] with gn bounds-check
//   (zeroes pads/edges). Replaces 5120 scalar 2B global gathers per block.
//   Main loop + XCD swizzle unchanged from R12. Other kernels unchanged.

#define B_  16
#define C_  512
#define N_  4096
#define OT  640

typedef __bf16 bf16x8 __attribute__((ext_vector_type(8)));
typedef float  f32x4  __attribute__((ext_vector_type(4)));

// ws layout (float offsets)
static constexpr size_t PBF_OFF = 0;                                  // bf16 B*640*N
static constexpr size_t XT_OFF  = ((size_t)B_ * OT * N_) / 2;         // bf16 B*N*C
static constexpr size_t WB_OFF  = XT_OFF + ((size_t)B_ * N_ * C_) / 2;
static constexpr size_t SB_OFF  = WB_OFF + ((size_t)OT * C_) / 2;
static constexpr size_t ST_OFF  = SB_OFF + (size_t)OT * 2;            // stats B*64*2 f32
static constexpr size_t LAM_OFF = ST_OFF + (size_t)B_ * 64 * 2;
// total ~152 MB

__device__ __forceinline__ void load_lds16(const void* g, void* l) {
  __builtin_amdgcn_global_load_lds(
      (const __attribute__((address_space(1))) void*)g,
      (__attribute__((address_space(3))) void*)l, 16, 0, 0);
}

__device__ __forceinline__ unsigned short f2bf(float f) {
  __hip_bfloat16 h = __float2bfloat16(f);
  return *(unsigned short*)&h;
}
__device__ __forceinline__ float bf2f(unsigned short u) {
  union { unsigned int i; float f; } c; c.i = ((unsigned int)u) << 16; return c.f;
}

// ---------------------------------------------------------------- K0: pack
__global__ __launch_bounds__(256) void pack_kernel(
    const float* __restrict__ Wq, const float* __restrict__ gq, const float* __restrict__ bq,
    const float* __restrict__ Wk, const float* __restrict__ Wv,
    const float* __restrict__ gv, const float* __restrict__ bv,
    __hip_bfloat16* __restrict__ Wall, float* __restrict__ sb) {
  int idx = blockIdx.x * 256 + threadIdx.x;
  if (idx < OT * C_) {
    int row = idx >> 9;  // /512
    float val;
    if (row < 64)        val = Wq[idx];
    else if (row < 128)  val = Wk[idx - 64 * C_];
    else                 val = Wv[idx - 128 * C_];
    Wall[idx] = __float2bfloat16(val);
  }
  if (idx < OT) {
    const float inv = 0.99999500003749971875f;  // 1/sqrt(1+1e-5)
    float s, bi;
    if (idx < 64)       { s = gq[idx] * inv;       bi = bq[idx]; }
    else if (idx < 128) { s = 1.0f;                bi = 0.0f; }
    else                { s = gv[idx - 128] * inv; bi = bv[idx - 128]; }
    sb[idx * 2]     = s;
    sb[idx * 2 + 1] = bi;
  }
}

// ---------------------------------------------------------------- K0b: x -> xT bf16 (B,N,C)
__global__ __launch_bounds__(256) void convert_x(
    const float* __restrict__ x, __hip_bfloat16* __restrict__ xT) {
  const int n0 = blockIdx.x * 64;
  const int c0 = blockIdx.y * 64;
  const int b  = blockIdx.z;
  __shared__ float tile[64][65];
  const int t = threadIdx.x;
  const int tr = t >> 4, tc4 = (t & 15) * 4;
  const float* xb = x + ((size_t)b * C_ + c0) * N_ + n0;
#pragma unroll
  for (int i = 0; i < 4; ++i) {
    float4 v = *(const float4*)&xb[(size_t)(i * 16 + tr) * N_ + tc4];
    *(float4*)&tile[i * 16 + tr][tc4] = v;
  }
  __syncthreads();
  __hip_bfloat16* ob = xT + ((size_t)b * N_ + n0) * C_ + c0;
#pragma unroll
  for (int i = 0; i < 4; ++i) {
    int rn = i * 16 + tr;
    uint2 pk;
    __hip_bfloat16* ph = (__hip_bfloat16*)&pk;
#pragma unroll
    for (int j = 0; j < 4; ++j) ph[j] = __float2bfloat16(tile[tc4 + j][rn]);
    *(uint2*)&ob[(size_t)rn * C_ + tc4] = pk;
  }
}

// ---------------------------------------------------------------- K1: MFMA proj GEMM (R7 structure)
__global__ __launch_bounds__(256) void gemm_mfma(
    const __hip_bfloat16* __restrict__ xT, const __hip_bfloat16* __restrict__ Wb,
    const float* __restrict__ sb, __hip_bfloat16* __restrict__ pbf) {
  const int t = threadIdx.x;
  const int l = t & 63, w = t >> 6;
  const int wr = w >> 1, wc = w & 1;
  const int m0 = blockIdx.y * 128, n0 = blockIdx.x * 128;
  const int b = blockIdx.z;
  const __hip_bfloat16* xb = xT + (size_t)b * N_ * C_;

  __shared__ __hip_bfloat16 Als[128 * 32];  // [m][k] row-major
  __shared__ __hip_bfloat16 Bls[128 * 32];  // [n][k] row-major

  const int srow = w * 16 + (l >> 2);
  const int scol = (l & 3) * 8;
  const __hip_bfloat16* gA = Wb + (size_t)(m0 + srow) * C_ + scol;
  const __hip_bfloat16* gB = xb + (size_t)(n0 + srow) * C_ + scol;
  __hip_bfloat16* lA = &Als[w * 512 + l * 8];
  __hip_bfloat16* lB = &Bls[w * 512 + l * 8];

  const int fr = l & 15;
  const int kg = (l >> 4) * 8;

  f32x4 acc[4][4] = {};

  for (int c0 = 0; c0 < C_; c0 += 32) {
    __syncthreads();
#pragma unroll
    for (int i = 0; i < 2; ++i) {
      load_lds16(gA + (size_t)i * 64 * C_ + c0, lA + i * 2048);
      load_lds16(gB + (size_t)i * 64 * C_ + c0, lB + i * 2048);
    }
    __syncthreads();
    bf16x8 af[4], bfr[4];
#pragma unroll
    for (int m = 0; m < 4; ++m)
      af[m] = *(const bf16x8*)&Als[(size_t)(wr * 64 + m * 16 + fr) * 32 + kg];
#pragma unroll
    for (int n = 0; n < 4; ++n)
      bfr[n] = *(const bf16x8*)&Bls[(size_t)(wc * 64 + n * 16 + fr) * 32 + kg];
#pragma unroll
    for (int m = 0; m < 4; ++m)
#pragma unroll
      for (int n = 0; n < 4; ++n)
        acc[m][n] = __builtin_amdgcn_mfma_f32_16x16x32_bf16(af[m], bfr[n], acc[m][n], 0, 0, 0);
  }

  __hip_bfloat16* pb = pbf + (size_t)b * OT * N_;
  const int rb = (l >> 4) * 4;
#pragma unroll
  for (int m = 0; m < 4; ++m) {
#pragma unroll
    for (int r = 0; r < 4; ++r) {
      int grow = m0 + wr * 64 + m * 16 + rb + r;
      float s = sb[grow * 2], bi = sb[grow * 2 + 1];
#pragma unroll
      for (int n = 0; n < 4; ++n) {
        int gcol = n0 + wc * 64 + n * 16 + fr;
        pb[(size_t)grow * N_ + gcol] = __float2bfloat16(acc[m][n][r] * s + bi);
      }
    }
  }
}

// ---------------------------------------------------------------- K2: key-row stats (max, 1/sum_exp)
__global__ __launch_bounds__(256) void softmax_stats(
    const __hip_bfloat16* __restrict__ pbf, float* __restrict__ stats) {
  const int r = blockIdx.x, b = blockIdx.y;
  const __hip_bfloat16* row = pbf + ((size_t)b * OT + 64 + r) * N_;
  const int t = threadIdx.x;
  float f[16];
  {
    uint4 v1 = ((const uint4*)row)[t];
    uint4 v2 = ((const uint4*)row)[t + 256];
    const unsigned short* h1 = (const unsigned short*)&v1;
    const unsigned short* h2 = (const unsigned short*)&v2;
#pragma unroll
    for (int j = 0; j < 8; ++j) { f[j] = bf2f(h1[j]); f[j + 8] = bf2f(h2[j]); }
  }
  float mx = -1e30f;
#pragma unroll
  for (int j = 0; j < 16; ++j) mx = fmaxf(mx, f[j]);
  __shared__ float red[4];
#pragma unroll
  for (int off = 32; off; off >>= 1) mx = fmaxf(mx, __shfl_xor(mx, off));
  if ((t & 63) == 0) red[t >> 6] = mx;
  __syncthreads();
  mx = fmaxf(fmaxf(red[0], red[1]), fmaxf(red[2], red[3]));
  float sum = 0.f;
#pragma unroll
  for (int j = 0; j < 16; ++j) sum += __expf(f[j] - mx);
  __syncthreads();
#pragma unroll
  for (int off = 32; off; off >>= 1) sum += __shfl_xor(sum, off);
  if ((t & 63) == 0) red[t >> 6] = sum;
  __syncthreads();
  if (t == 0) {
    float s = red[0] + red[1] + red[2] + red[3];
    stats[((size_t)b * 64 + r) * 2]     = mx;
    stats[((size_t)b * 64 + r) * 2 + 1] = 1.0f / s;
  }
}

// ---------------------------------------------------------------- K3: lambda_c (MFMA, vh merged)
__global__ __launch_bounds__(256) void lambda_c_kernel(
    const __hip_bfloat16* __restrict__ pbf, const float* __restrict__ stats,
    float* __restrict__ lam) {
  const int ns = blockIdx.x;
  const int b  = blockIdx.y;
  const int nb = ns * 128;
  const int t = threadIdx.x, l = t & 63, w = t >> 6;
  __shared__ __hip_bfloat16 klds[64 * 128];  // XOR-swizzled, 16 KB

  const __hip_bfloat16* kg = pbf + ((size_t)b * OT + 64) * N_ + nb;
  const float* stb = stats + (size_t)b * 64 * 2;
#pragma unroll
  for (int i = 0; i < 4; ++i) {
    int task = i * 256 + t;            // 1024 x 16B
    int row = task >> 4, gc = task & 15;
    uint4 val = *(const uint4*)&kg[(size_t)row * N_ + gc * 8];
    float mx = stb[row * 2], ivs = stb[row * 2 + 1];
    unsigned short* hs = (unsigned short*)&val;
#pragma unroll
    for (int j = 0; j < 8; ++j)
      hs[j] = f2bf(__expf(bf2f(hs[j]) - mx) * ivs);
    int byte = (row * 256 + gc * 16) ^ (((row >> 2) & 7) << 4);
    *(uint4*)((char*)klds + byte) = val;
  }
  __syncthreads();

  const int fr = l & 15, g = l >> 4;
  const __hip_bfloat16* vg = pbf + ((size_t)b * OT + 128) * N_ + nb;
  float* lamb = lam + (size_t)b * 16 * 128;
#pragma unroll
  for (int vt = 0; vt < 2; ++vt) {
    const int vv0 = (vt * 4 + w) * 16;
    f32x4 acc = {};
#pragma unroll
    for (int ui = 0; ui < 4; ++ui) {
#pragma unroll
      for (int s = 0; s < 4; ++s) {
        const int krow = fr * 4 + ui;
        const int byte = (krow * 256 + s * 64 + g * 16) ^ (((krow >> 2) & 7) << 4);
        bf16x8 af = *(const bf16x8*)((const char*)klds + byte);
        const int vrow = (vv0 + fr) * 4 + ui;
        bf16x8 bf = *(const bf16x8*)&vg[(size_t)vrow * N_ + s * 32 + g * 8];
        acc = __builtin_amdgcn_mfma_f32_16x16x32_bf16(af, bf, acc, 0, 0, 0);
      }
    }
#pragma unroll
    for (int r = 0; r < 4; ++r)
      atomicAdd(&lamb[(g * 4 + r) * 128 + vv0 + fr], acc[r]);
  }
}

// ---------------------------------------------------------------- K4: final (load_lds staging + repack)
// flat grid 8192, XCD swizzle. Pstg[ui][vl][64]: window gn = n0-8 .. n0+55,
// per-lane 16B chunks, edge-clamped (clamped chunks cover only invalid gn).
// Repack: (vl,np) -> 4 u16 plane reads (s=np+5) with gn bounds-check -> b64 write.
__global__ __launch_bounds__(256) void final_kernel(
    const __hip_bfloat16* __restrict__ pbf, const float* __restrict__ lam,
    const float* __restrict__ emb, float* __restrict__ out) {
  const int swz = (blockIdx.x & 7) * 1024 + (blockIdx.x >> 3);
  const int b   = swz >> 9;
  const int vq  = (swz >> 7) & 3;
  const int n0  = (swz & 127) * 32;
  const int vv0 = vq * 32;
  const __hip_bfloat16* qb = pbf + (size_t)b * OT * N_;
  const __hip_bfloat16* vb = pbf + ((size_t)b * OT + 128) * N_;
  const int t = threadIdx.x, l = t & 63, w = t >> 6;

  __shared__ __hip_bfloat16 Pstg[4][32][64];    // 16,384 B planes [ui][vl][s]
  __shared__ __hip_bfloat16 P_lds[32][40][4];   // 10,240 B packed
  __shared__ float lamT[32][16];                //  2,048 B

  const int fr = l & 15;         // A k-row / B nl-col / D col
  const int g  = l >> 4;         // K-group
  const int rb = g * 4;          // D row base (k)
  const int gb0 = g & 1, gb1 = g >> 1;

  // ---- stage P planes: 128 rows x 128B; 4 issues/wave; lane = (row l>>3, chunk l&7)
#pragma unroll
  for (int i = 0; i < 4; ++i) {
    int R  = i * 32 + w * 8 + (l >> 3);   // 0..127
    int ui = R >> 5, vl = R & 31;
    int gn0 = n0 - 8 + (l & 7) * 8;
    gn0 = gn0 < 0 ? 0 : (gn0 > N_ - 8 ? N_ - 8 : gn0);
    const __hip_bfloat16* src = &vb[(size_t)(ui * 128 + vv0 + vl) * N_ + gn0];
    load_lds16(src, (char*)Pstg + (size_t)(i * 32 + w * 8) * 128 + (size_t)l * 16);
  }

  // emb A-frag: lane holds emb[k=fr][kap=g*8+j], kap=(dm*4+ui), 0 for kap>=28
  union { uint4 u; bf16x8 v; } ef;
  {
    unsigned short eh[8];
#pragma unroll
    for (int j = 0; j < 8; ++j) {
      int kap = g * 8 + j;
      float val = 0.f;
      if (kap < 28) val = emb[fr * 28 + (kap & 3) * 7 + (kap >> 2)];
      eh[j] = f2bf(val);
    }
    ef.u.x = eh[0] | ((unsigned)eh[1] << 16);
    ef.u.y = eh[2] | ((unsigned)eh[3] << 16);
    ef.u.z = eh[4] | ((unsigned)eh[5] << 16);
    ef.u.w = eh[6] | ((unsigned)eh[7] << 16);
  }

  // q preload (bf16)
  float qreg[4][4][2];
#pragma unroll
  for (int hh = 0; hh < 4; ++hh)
#pragma unroll
    for (int r = 0; r < 4; ++r)
#pragma unroll
      for (int nt = 0; nt < 2; ++nt)
        qreg[hh][r][nt] = bf2f(*(const unsigned short*)
            &qb[(size_t)(hh * 16 + rb + r) * N_ + n0 + nt * 16 + fr]);

  // lamT
  {
    int kk = t >> 5, vl = t & 31;
    lamT[vl][kk]     = lam[((size_t)b * 16 + kk) * 128 + vv0 + vl];
    lamT[vl][kk + 8] = lam[((size_t)b * 16 + kk + 8) * 128 + vv0 + vl];
  }
  __syncthreads();   // drains vmcnt(0) for load_lds before plane reads

  // ---- repack planes -> packed P_lds (bounds-check zeroes pads/edges)
#pragma unroll
  for (int i = 0; i < 5; ++i) {
    int task = i * 256 + t;              // 1280 = 32 vl * 40 np
    int vl = task / 40;
    int np = task - vl * 40;
    int gn = n0 + np - 3;
    unsigned short hv[4];
    if (np < 38 && gn >= 0 && gn < N_) {
      int s = np + 5;                    // s = gn - (n0-8)
#pragma unroll
      for (int ui = 0; ui < 4; ++ui)
        hv[ui] = *(const unsigned short*)&Pstg[ui][vl][s];
    } else {
      hv[0] = hv[1] = hv[2] = hv[3] = 0;
    }
    uint2 pk;
    pk.x = hv[0] | ((unsigned)hv[1] << 16);
    pk.y = hv[2] | ((unsigned)hv[3] << 16);
    *(uint2*)&P_lds[vl][np][0] = pk;
  }
  __syncthreads();

  float* obase = out + ((size_t)b * 512 + g * 128 + vv0) * N_ + n0;
#pragma unroll
  for (int mi = 0; mi < 16; ++mi) {
    const int vl_t = w * 8 + (mi >> 1);
    const int nt   = mi & 1;
    const int nlc  = nt * 16 + fr;
    union { uint4 u; bf16x8 v; } bf;
    {
      const uint2 lo = *(const uint2*)&P_lds[vl_t][nlc + 2 * g][0];
      const uint2 hi = *(const uint2*)&P_lds[vl_t][nlc + 2 * g + 1][0];
      bf.u.x = lo.x; bf.u.y = lo.y; bf.u.z = hi.x; bf.u.w = hi.y;
    }
    f32x4 c = *(const f32x4*)&lamT[vl_t][rb];
    f32x4 d = __builtin_amdgcn_mfma_f32_16x16x32_bf16(ef.v, bf.v, c, 0, 0, 0);
    float p0 = qreg[0][0][nt] * d[0] + qreg[0][1][nt] * d[1] + qreg[0][2][nt] * d[2] + qreg[0][3][nt] * d[3];
    float p1 = qreg[1][0][nt] * d[0] + qreg[1][1][nt] * d[1] + qreg[1][2][nt] * d[2] + qreg[1][3][nt] * d[3];
    float p2 = qreg[2][0][nt] * d[0] + qreg[2][1][nt] * d[1] + qreg[2][2][nt] * d[2] + qreg[2][3][nt] * d[3];
    float p3 = qreg[3][0][nt] * d[0] + qreg[3][1][nt] * d[1] + qreg[3][2][nt] * d[2] + qreg[3][3][nt] * d[3];
    float e0 = gb0 ? p0 : p1;
    float e1 = gb0 ? p2 : p3;
    float s0 = (gb0 ? p1 : p0) + __shfl_xor(e0, 16);
    float s1 = (gb0 ? p3 : p2) + __shfl_xor(e1, 16);
    float e2 = gb1 ? s0 : s1;
    float yv = (gb1 ? s1 : s0) + __shfl_xor(e2, 32);
    obase[(size_t)vl_t * N_ + nlc] = yv;
  }
}

// ---------------------------------------------------------------- launch
extern "C" void kernel_launch(void* const* d_in, const int* in_sizes, int n_in,
                              void* d_out, int out_size, void* d_ws, size_t ws_size,
                              hipStream_t stream) {
  const float* x   = (const float*)d_in[0];
  const float* Wq  = (const float*)d_in[1];
  const float* gq  = (const float*)d_in[2];
  const float* bq  = (const float*)d_in[3];
  const float* Wk  = (const float*)d_in[4];
  const float* Wv  = (const float*)d_in[5];
  const float* gv  = (const float*)d_in[6];
  const float* bv  = (const float*)d_in[7];
  const float* emb = (const float*)d_in[8];

  float* ws = (float*)d_ws;
  __hip_bfloat16* pbf   = (__hip_bfloat16*)(ws + PBF_OFF);
  __hip_bfloat16* xTb   = (__hip_bfloat16*)(ws + XT_OFF);
  __hip_bfloat16* Wallb = (__hip_bfloat16*)(ws + WB_OFF);
  float* sb    = ws + SB_OFF;
  float* stats = ws + ST_OFF;
  float* lam   = ws + LAM_OFF;
  float* out   = (float*)d_out;

  hipMemsetAsync(lam, 0, (size_t)B_ * 16 * 128 * sizeof(float), stream);
  pack_kernel<<<dim3(1280), 256, 0, stream>>>(Wq, gq, bq, Wk, Wv, gv, bv, Wallb, sb);
  convert_x<<<dim3(N_ / 64, C_ / 64, B_), 256, 0, stream>>>(x, xTb);
  gemm_mfma<<<dim3(N_ / 128, OT / 128, B_), 256, 0, stream>>>(xTb, Wallb, sb, pbf);
  softmax_stats<<<dim3(64, B_), 256, 0, stream>>>(pbf, stats);
  lambda_c_kernel<<<dim3(32, 16), 256, 0, stream>>>(pbf, stats, lam);
  final_kernel<<<dim3(8192), 256, 0, stream>>>(pbf, lam, emb, out);
}